// Round 7
// baseline (254.394 us; speedup 1.0000x reference)
//
#include <hip/hip_runtime.h>
#include <hip/hip_cooperative_groups.h>

namespace cg = cooperative_groups;

#define NPIX 4096
#define NB   128
#define NA   10
#define HCH  150
#define NT   512     // 512 thr -> empirical 128-VGPR budget (R1-R6 law)
#define VS   68      // LDS row stride for obs/r/v tiles
#define OROWS 40     // obs rows staged: [base-4, base+36)
#define RROWS 36     // r rows: [base-2, base+34)
#define VR    34     // v rows: halo + 32 own + halo
#define OBSF (2 * OROWS * VS)   // 5440 floats; later aliased as vlds (VR*VS=2312)
#define WHRF 4200               // Wh|Wr|bh staging; later aliased as rlds (36*68=2448)
#define PADF 10336   // pad -> 81,952 B total LDS > 81,920 -> exactly 1 block/CU

// ---------------------------------------------------------------------------
// Full-chip VIN: cooperative launch, 256 blocks = 2 per image (half = bid>>7,
// rows [half*32, half*32+32)). R6 forensics: VI runs ~all K=64 sweeps (exit
// never fires; info travels ~1 row/sweep on a 64-row grid) at the VALU issue
// floor of HALF the chip (128 blocks / 256 CUs). This version halves per-CU
// work by spatial split; the single boundary v-row is exchanged through d_ws
// with device-scope relaxed atomics every sweep (stale-by-few-sweeps = benign
// contraction race, same argument as the verified in-block async sweeps).
// Each block computes r two rows past its boundary so it can locally init the
// halo v0 (no dependence on neighbor's progress); one grid.sync() after the
// initial halo publish guarantees no block ever reads unwritten/poisoned ws.
// Convergence-check machinery removed (measured: pure overhead). Fixed K
// sweeps; intra-block drift bounded by a barrier every 4 sweeps (R6 protocol).
// LDS padded >80 KB: cooperative capacity = exactly 1 block/CU -> guaranteed
// spread + co-residency. Live set ~85 regs (qr[4][10]+vn[4][4]+w[9]) < 128.
// ---------------------------------------------------------------------------
__global__ __launch_bounds__(NT) void vin_fused(
        const float* __restrict__ obs,    // [128][2][64][64]
        const float* __restrict__ Wh,     // [150][2][9]
        const float* __restrict__ bh,     // [150]
        const float* __restrict__ Wr,     // [150][9]
        const float* __restrict__ Wi,     // w_i2q [10][9]
        const float* __restrict__ Wvq,    // w_v2q [10][9]
        const float* __restrict__ Wfc,    // [8][10]
        const int* __restrict__ s1, const int* __restrict__ s2,
        const int* __restrict__ kptr,
        float* __restrict__ hal,          // d_ws: [128][2][64] halo slots
        float* __restrict__ out) {        // [128][8]
    __shared__ float poolA[OBSF];   // obs[2][40][68] -> vlds[34][68]
    __shared__ float poolB[WHRF];   // Wh|Wr|bh       -> rlds[36][68]
    __shared__ float kb[222];       // K5[50] C@50 M[162]@51 Bd[9]@213
    __shared__ float wil[90];
    __shared__ float wvl12[120];    // w_v2q stride-12 (16B-aligned rows)
    __shared__ float wfcl[80];
    __shared__ float ldspad[PADF];  // occupancy shaper: 1 block/CU
    int tid  = threadIdx.x;
    int bid  = blockIdx.x;
    int img  = bid & (NB - 1);
    int half = bid >> 7;
    int base = half << 5;

    // ---------------- phase 1: stage obs slab + weights ----------------
    const float* ob_g = obs + (size_t)img * 2 * NPIX;
    for (int i = tid; i < 2 * OROWS * 64; i += NT) {
        int ch = i / (OROWS * 64), rem = i % (OROWS * 64);
        int orow = rem >> 6, x = rem & 63;
        int g = base - 4 + orow;
        poolA[ch * (OROWS * VS) + orow * VS + x + 2] =
            (g >= 0 && g < 64) ? ob_g[ch * NPIX + g * 64 + x] : 0.f;
    }
    for (int i = tid; i < 2 * OROWS * 4; i += NT) {   // zero pad cols 0,1,66,67
        int ch = i / (OROWS * 4), rem = i % (OROWS * 4);
        int orow = rem >> 2, c = rem & 3;
        int col = (c < 2) ? c : 64 + c;
        poolA[ch * (OROWS * VS) + orow * VS + col] = 0.f;
    }
    for (int i = tid; i < 2700; i += NT) poolB[i] = Wh[i];
    for (int i = tid; i < 1350; i += NT) poolB[2700 + i] = Wr[i];
    if (tid < 150) poolB[4050 + tid] = bh[tid];
    if (tid < 90) { wil[tid] = Wi[tid]; wvl12[(tid / 9) * 12 + tid % 9] = Wvq[tid]; }
    if (tid < 80) wfcl[tid] = Wfc[tid];
    int K = kptr[0];
    int att_y = 0, att_x = 0;
    if (tid == 0) { att_y = s1[img]; att_x = s2[img]; }
    __syncthreads();

    // ---------------- phase 2: composed-kernel precompute (verbatim) --------
    {
        int wvid = tid >> 6, lane = tid & 63;   // 8 waves
        const float* WhL = poolB;
        const float* WrL = poolB + 2700;
        const float* bhL = poolB + 4050;
        for (int o = wvid; o < 222; o += 8) {
            float s = 0.f;
            if (o < 50) {
                int ci = o / 25, uv = o % 25, u = uv / 5, v = uv % 5;
                for (int ch = lane; ch < HCH; ch += 64) {
                    const float* wr = WrL + ch * 9;
                    const float* wh = WhL + ch * 18 + ci * 9;
                    for (int ky = 0; ky < 3; ++ky) {
                        int ey = u - ky; if (ey < 0 || ey > 2) continue;
                        for (int kx = 0; kx < 3; ++kx) {
                            int ex = v - kx; if (ex < 0 || ex > 2) continue;
                            s += wr[ky * 3 + kx] * wh[ey * 3 + ex];
                        }
                    }
                }
            } else if (o == 50) {
                for (int ch = lane; ch < HCH; ch += 64) {
                    float wsum = 0.f;
                    for (int t = 0; t < 9; ++t) wsum += WrL[ch * 9 + t];
                    s += wsum * bhL[ch];
                }
            } else if (o < 213) {
                int m = o - 51;
                int d = m / 18, rest = m % 18, ci = rest / 9, e = rest % 9;
                for (int ch = lane; ch < HCH; ch += 64)
                    s += WrL[ch * 9 + d] * WhL[ch * 18 + ci * 9 + e];
            } else {
                int d = o - 213;
                for (int ch = lane; ch < HCH; ch += 64)
                    s += WrL[ch * 9 + d] * bhL[ch];
            }
            #pragma unroll
            for (int off = 32; off > 0; off >>= 1) s += __shfl_down(s, off);
            if (lane == 0) kb[o] = s;
        }
    }
    __syncthreads();

    // ---------------- phase 3: r rows [base-2, base+34) into poolB ----------
    float* rlds = poolB;                        // whr dead after phase 2
    for (int i = tid; i < RROWS * 4; i += NT) { // zero pad cols 0,65,66,67
        int row = i >> 2, c = i & 3;
        int col = (c == 0) ? 0 : 64 + c;
        rlds[row * VS + col] = 0.f;
    }
    for (int idx = tid; idx < RROWS * 64; idx += NT) {
        int m = idx >> 6, x = idx & 63;
        int g = base - 2 + m;
        float val = 0.f;
        if (g >= 0 && g < 64) {
            const float* o0 = poolA;
            const float* o1 = poolA + OROWS * VS;
            float acc = kb[50];
            #pragma unroll
            for (int u = 0; u < 5; ++u)
                #pragma unroll
                for (int v = 0; v < 5; ++v)
                    acc += kb[u * 5 + v]      * o0[(m + u) * VS + x + v]
                         + kb[25 + u * 5 + v] * o1[(m + u) * VS + x + v];
            if (g == 0 || g == 63 || x == 0 || x == 63) {
                for (int d = 0; d < 9; ++d) {
                    int ny = g + d / 3 - 1, nx = x + d % 3 - 1;
                    if (ny >= 0 && ny <= 63 && nx >= 0 && nx <= 63) continue;
                    float corr = kb[213 + d];
                    for (int e = 0; e < 9; ++e) {
                        int oy = ny + e / 3 - 1, ox = nx + e % 3 - 1;
                        if (oy < 0 || oy > 63 || ox < 0 || ox > 63) continue;
                        corr += kb[51 + d * 18 + e]     * o0[(oy - base + 4) * VS + ox + 2]
                              + kb[51 + d * 18 + 9 + e] * o1[(oy - base + 4) * VS + ox + 2];
                    }
                    acc -= corr;
                }
            }
            val = acc;
        }
        rlds[m * VS + x + 1] = val;
    }
    __syncthreads();                            // obs reads done; poolA retires

    // ---------------- phase 4: vlds init, qr, v0 (own + interior halo) ------
    float* vlds = poolA;
    for (int i = tid; i < VR * VS; i += NT) vlds[i] = 0.f;
    __syncthreads();

    int tx = tid & 31, ty = tid >> 5;           // 32 x 16 threads, 2x2 patch
    int x0 = tx << 1;
    float qr[4][NA];
    #pragma unroll
    for (int py = 0; py < 2; ++py)
        #pragma unroll
        for (int px = 0; px < 2; ++px) {
            int lrow = (ty << 1) + 1 + py;      // vlds row 1..32
            float rn[9];
            #pragma unroll
            for (int t = 0; t < 9; ++t)
                rn[t] = rlds[(lrow + t / 3) * VS + x0 + px + t % 3];
            float vmax = -1e30f;
            #pragma unroll
            for (int a = 0; a < NA; ++a) {
                float acc = 0.f;
                #pragma unroll
                for (int t = 0; t < 9; ++t) acc += wil[a * 9 + t] * rn[t];
                qr[py * 2 + px][a] = acc;
                vmax = fmaxf(vmax, acc);
            }
            vlds[lrow * VS + x0 + px + 1] = vmax;
        }
    // interior-halo v0 (neighbor's edge row), computed locally from own r halo
    int HB = (half == 0) ? 33 : 0;   // r-row base == vlds halo row index
    if (tid < 64) {
        float rn[9];
        #pragma unroll
        for (int t = 0; t < 9; ++t)
            rn[t] = rlds[(HB + t / 3) * VS + tid + t % 3];
        float vmax = -1e30f;
        #pragma unroll
        for (int a = 0; a < NA; ++a) {
            float acc = 0.f;
            #pragma unroll
            for (int t = 0; t < 9; ++t) acc += wil[a * 9 + t] * rn[t];
            vmax = fmaxf(vmax, acc);
        }
        vlds[HB * VS + tid + 1] = vmax;
    }
    __syncthreads();

    // publish own edge v0, then grid-wide sync (halo slots valid before reads)
    float* hs = hal + img * 128;
    int EL = (half == 0) ? 32 : 1;              // own edge row in vlds
    if (tid >= 64 && tid < 128) {
        int c = tid - 64;
        __hip_atomic_store(&hs[half * 64 + c], vlds[EL * VS + c + 1],
                           __ATOMIC_RELAXED, __HIP_MEMORY_SCOPE_AGENT);
    }
    cg::grid_group grid = cg::this_grid();
    grid.sync();

    // ---------------- phase 5: K async sweeps (no convergence check) --------
    int y0l = ty << 1;
    for (int it = 0; it < K; ++it) {
        float hv = 0.f;                          // issue halo load early; consume late
        if (tid < 64)
            hv = __hip_atomic_load(&hs[(1 - half) * 64 + tid],
                                   __ATOMIC_RELAXED, __HIP_MEMORY_SCOPE_AGENT);
        float vn[4][4];
        #pragma unroll
        for (int r = 0; r < 4; ++r) {
            const float2* vp = reinterpret_cast<const float2*>(&vlds[(y0l + r) * VS + x0]);
            float2 a0 = vp[0], a1 = vp[1];
            vn[r][0] = a0.x; vn[r][1] = a0.y; vn[r][2] = a1.x; vn[r][3] = a1.y;
        }
        float nv[4] = {-1e30f, -1e30f, -1e30f, -1e30f};
        #pragma unroll
        for (int a = 0; a < NA; ++a) {
            float4 w0 = *reinterpret_cast<const float4*>(&wvl12[a * 12]);
            float4 w1 = *reinterpret_cast<const float4*>(&wvl12[a * 12 + 4]);
            float w[9] = {w0.x, w0.y, w0.z, w0.w, w1.x, w1.y, w1.z, w1.w,
                          wvl12[a * 12 + 8]};
            #pragma unroll
            for (int py = 0; py < 2; ++py)
                #pragma unroll
                for (int px = 0; px < 2; ++px) {
                    float acc = qr[py * 2 + px][a];
                    #pragma unroll
                    for (int ky = 0; ky < 3; ++ky)
                        #pragma unroll
                        for (int kx = 0; kx < 3; ++kx)
                            acc += w[ky * 3 + kx] * vn[py + ky][px + kx];
                    nv[py * 2 + px] = fmaxf(nv[py * 2 + px], acc);
                }
        }
        #pragma unroll
        for (int py = 0; py < 2; ++py)
            #pragma unroll
            for (int px = 0; px < 2; ++px)
                vlds[(y0l + 1 + py) * VS + x0 + 1 + px] = nv[py * 2 + px];
        __threadfence_block();   // visibility + defeat LDS caching (R6 protocol)
        if (tid < 64) {
            vlds[HB * VS + tid + 1] = hv;        // halo refresh (stale<=1: benign)
        } else if (tid < 128) {
            int c = tid - 64;                     // publish own edge (stale<=1: benign)
            __hip_atomic_store(&hs[half * 64 + c], vlds[EL * VS + c + 1],
                               __ATOMIC_RELAXED, __HIP_MEMORY_SCOPE_AGENT);
        }
        if ((it & 3) == 3) __syncthreads();       // bound intra-block drift
    }
    __syncthreads();

    // ---------------- phase 6: attended q + FC (owning block only) ----------
    if (tid == 0 && (att_y >> 5) == half) {
        int lr = att_y - base + 1;
        float q[NA];
        #pragma unroll
        for (int a = 0; a < NA; ++a) {
            float acc = 0.f;
            #pragma unroll
            for (int t = 0; t < 9; ++t)
                acc += wil[a * 9 + t]    * rlds[(lr + t / 3) * VS + att_x + t % 3]
                     + wvl12[a * 12 + t] * vlds[(lr - 1 + t / 3) * VS + att_x + t % 3];
            q[a] = acc;
        }
        #pragma unroll
        for (int n = 0; n < 8; ++n) {
            float o = 0.f;
            #pragma unroll
            for (int a = 0; a < NA; ++a) o += q[a] * wfcl[n * NA + a];
            out[img * 8 + n] = o;
        }
    }

    // keep-alive for ldspad (K >= 0 always; compiler can't prove it)
    if (K < 0) {
        ldspad[tid] = (float)tid;
        out[img * 8 + (tid & 7)] = ldspad[(PADF - 1) - tid];
    }
}

// ---------------------------------------------------------------------------
extern "C" void kernel_launch(void* const* d_in, const int* in_sizes, int n_in,
                              void* d_out, int out_size, void* d_ws, size_t ws_size,
                              hipStream_t stream) {
    const int*   s1   = (const int*)d_in[0];
    const int*   s2   = (const int*)d_in[1];
    const float* obs  = (const float*)d_in[2];
    const int*   kptr = (const int*)d_in[3];
    const float* Wh   = (const float*)d_in[4];
    const float* bh   = (const float*)d_in[5];
    const float* Wr   = (const float*)d_in[6];
    const float* Wi   = (const float*)d_in[7];
    const float* Wvq  = (const float*)d_in[8];
    const float* Wfc  = (const float*)d_in[9];
    float* out = (float*)d_out;
    float* hal = (float*)d_ws;   // 128*2*64 floats = 32 KB halo slots
    (void)ws_size; (void)in_sizes; (void)n_in; (void)out_size;

    void* args[] = {(void*)&obs, (void*)&Wh, (void*)&bh, (void*)&Wr,
                    (void*)&Wi,  (void*)&Wvq, (void*)&Wfc,
                    (void*)&s1,  (void*)&s2,  (void*)&kptr,
                    (void*)&hal, (void*)&out};
    hipLaunchCooperativeKernel((const void*)vin_fused, dim3(2 * NB), dim3(NT),
                               args, 0, stream);
}

// Round 8
// 144.209 us; speedup vs baseline: 1.7641x; 1.7641x over previous
//
#include <hip/hip_runtime.h>

#define HW 64
#define NPIX 4096
#define NB 128
#define NA 10
#define HCH 150
#define NT 512       // 512 thr -> empirical 128-VGPR budget (R1-R6 law)
#define VS 68        // LDS row stride for r/v (64 + 2 ring + pad)
#define VROWS 66
#define POOLF (2 * VROWS * VS)   // 8976 floats: rlds | vlds (aliases obs region)
#define OS 66        // obs LDS row stride
#define OPL (64 * OS) // obs LDS plane stride (4224)
#define PADF 7104    // pad -> 82,016 B total LDS > 81,920 -> exactly 1 block/CU

// ---------------------------------------------------------------------------
// Single fused kernel. One block per batch image. 512 threads, 4x2 patch.
//
// R7 lesson: cross-block VI (per-sweep agent-scope halo atomics) de-optimizes
// the loop 6x in VALU-cycles -> reverted to the R6 single-block-per-image
// structure. R6's remaining bottleneck (theory): 60 LDS weight-read
// instructions per thread-sweep serialize on the per-CU LDS pipe (~2.5
// us/sweep) vs a 1.4 us/sweep VALU floor. Fix: VI weights are wave-uniform
// with compile-time indices -> read Wvq DIRECTLY from the kernel arg
// (s_load into SGPRs, loop-invariant, scalar cache; inner op becomes
// v_fmac_f32 v,s,v). Zero LDS/VGPR cost for weights -> vn re-merged to
// [6][4] (live ~120 < 128, spill-free), vn loads float2-vectorized,
// `changed` computed only on check sweeps. wil/wvl/wfc LDS staging deleted
// (all uniform-indexed -> scalar loads). VI protocol verbatim otherwise
// (tol 4e-4, check every 4th sweep, async in-place between checks; early
// exit DOES fire: R6 absmax 1.9e-6 vs full-K bitwise-0 in R7).
// LDS pad keeps 1 block/CU (R5: +18 us).
// ---------------------------------------------------------------------------
__global__ __launch_bounds__(NT) void vin_fused(
        const float* __restrict__ obs,    // [128][2][64][64]
        const float* __restrict__ Wh,     // [150][2][9]
        const float* __restrict__ bh,     // [150]
        const float* __restrict__ Wr,     // [150][9]
        const float* __restrict__ Wi,     // w_i2q [10][9]
        const float* __restrict__ Wvq,    // w_v2q [10][9]
        const float* __restrict__ Wfc,    // [8][10]
        const int* __restrict__ s1, const int* __restrict__ s2,
        const int* __restrict__ kptr,
        float* __restrict__ out) {        // [128][8]
    __shared__ float pool[POOLF];   // phase 1-3: obs[2][64][66]; phase 4+: rlds|vlds
    __shared__ float whr[4200];     // Wh[2700] | Wr[1350->@2700] | bh[150->@4050]
    __shared__ float kb[222];       // K5[50] C[1]@50 M[162]@51 Bd[9]@213
    __shared__ int   chg[2];
    __shared__ float ldspad[PADF];  // occupancy shaper: forces 1 block/CU
    int tid = threadIdx.x;
    int b = blockIdx.x;

    // ---------------- phase 1: stage obs + conv weights ----------------
    const float* ob_g = obs + (size_t)b * 2 * NPIX;
    for (int i = tid; i < 2 * NPIX; i += NT) {
        int ch = i >> 12, p = i & 4095, y = p >> 6, x = p & 63;
        pool[ch * OPL + y * OS + x] = ob_g[i];
    }
    for (int i = tid; i < 2700; i += NT) whr[i] = Wh[i];
    for (int i = tid; i < 1350; i += NT) whr[2700 + i] = Wr[i];
    if (tid < 150) whr[4050 + tid] = bh[tid];
    if (tid < 2)  chg[tid] = 0;
    int K = kptr[0];
    int att_y = 0, att_x = 0;
    if (tid == 0) { att_y = s1[b]; att_x = s2[b]; }   // tid0-only regs
    __syncthreads();

    // ---------------- phase 2: composed-kernel precompute (per wave) --------
    {
        int wvid = tid >> 6, lane = tid & 63;   // 8 waves
        const float* WhL = whr;
        const float* WrL = whr + 2700;
        const float* bhL = whr + 4050;
        for (int o = wvid; o < 222; o += 8) {
            float s = 0.f;
            if (o < 50) {
                int ci = o / 25, uv = o % 25, u = uv / 5, v = uv % 5;
                for (int ch = lane; ch < HCH; ch += 64) {
                    const float* wr = WrL + ch * 9;
                    const float* wh = WhL + ch * 18 + ci * 9;
                    for (int ky = 0; ky < 3; ++ky) {
                        int ey = u - ky; if (ey < 0 || ey > 2) continue;
                        for (int kx = 0; kx < 3; ++kx) {
                            int ex = v - kx; if (ex < 0 || ex > 2) continue;
                            s += wr[ky * 3 + kx] * wh[ey * 3 + ex];
                        }
                    }
                }
            } else if (o == 50) {
                for (int ch = lane; ch < HCH; ch += 64) {
                    float wsum = 0.f;
                    for (int t = 0; t < 9; ++t) wsum += WrL[ch * 9 + t];
                    s += wsum * bhL[ch];
                }
            } else if (o < 213) {
                int m = o - 51;
                int d = m / 18, rest = m % 18, ci = rest / 9, e = rest % 9;
                for (int ch = lane; ch < HCH; ch += 64)
                    s += WrL[ch * 9 + d] * WhL[ch * 18 + ci * 9 + e];
            } else {
                int d = o - 213;
                for (int ch = lane; ch < HCH; ch += 64)
                    s += WrL[ch * 9 + d] * bhL[ch];
            }
            #pragma unroll
            for (int off = 32; off > 0; off >>= 1) s += __shfl_down(s, off);
            if (lane == 0) kb[o] = s;
        }
    }
    __syncthreads();

    // ---------------- phase 3: r in registers (4x2 patch) ----------------
    int tx = tid & 31, ty = tid >> 5;   // 32 x 16 threads
    int x0 = tx * 2, y0 = ty * 4;       // thread owns 4-row x 2-col patch
    float r8[8];
    {
        // zero-padded obs window: rows y0-2..y0+5, cols x0-2..x0+3
        float ow[2][8][6];
        #pragma unroll
        for (int ch = 0; ch < 2; ++ch)
            #pragma unroll
            for (int r = 0; r < 8; ++r) {
                int gy = y0 + r - 2;
                bool yok = (gy >= 0 && gy <= 63);
                #pragma unroll
                for (int c = 0; c < 6; ++c) {
                    int gx = x0 + c - 2;
                    ow[ch][r][c] = (yok && gx >= 0 && gx <= 63)
                        ? pool[ch * OPL + gy * OS + gx] : 0.f;
                }
            }
        float acc[8];
        float C0 = kb[50];
        #pragma unroll
        for (int p = 0; p < 8; ++p) acc[p] = C0;
        #pragma unroll
        for (int u = 0; u < 5; ++u)
            #pragma unroll
            for (int v = 0; v < 5; ++v) {
                float k0 = kb[u * 5 + v];
                float k1 = kb[25 + u * 5 + v];
                #pragma unroll
                for (int py = 0; py < 4; ++py)
                    #pragma unroll
                    for (int px = 0; px < 2; ++px)
                        acc[py * 2 + px] += k0 * ow[0][py + u][px + v]
                                          + k1 * ow[1][py + u][px + v];
            }
        // exact border corrections (edge pixels only)
        #pragma unroll
        for (int py = 0; py < 4; ++py)
            #pragma unroll
            for (int px = 0; px < 2; ++px) {
                int y = y0 + py, x = x0 + px;
                if (y != 0 && y != 63 && x != 0 && x != 63) continue;
                for (int d = 0; d < 9; ++d) {
                    int ny = y + d / 3 - 1, nx = x + d % 3 - 1;
                    if (ny >= 0 && ny <= 63 && nx >= 0 && nx <= 63) continue;
                    float corr = kb[213 + d];
                    for (int e = 0; e < 9; ++e) {
                        int oy = ny + e / 3 - 1, ox = nx + e % 3 - 1;
                        if (oy < 0 || oy > 63 || ox < 0 || ox > 63) continue;
                        corr += kb[51 + d * 18 + e]     * pool[oy * OS + ox]
                              + kb[51 + d * 18 + 9 + e] * pool[OPL + oy * OS + ox];
                    }
                    acc[py * 2 + px] -= corr;
                }
            }
        #pragma unroll
        for (int p = 0; p < 8; ++p) r8[p] = acc[p];
    }
    __syncthreads();                       // all obs reads done; pool retires

    // ---------------- phase 4: pool becomes rlds|vlds ----------------
    for (int i = tid; i < POOLF; i += NT) pool[i] = 0.f;
    __syncthreads();
    float* rlds = pool;
    float* vlds = pool + VROWS * VS;
    #pragma unroll
    for (int py = 0; py < 4; ++py)
        #pragma unroll
        for (int px = 0; px < 2; ++px)
            rlds[(y0 + py + 1) * VS + (x0 + px + 1)] = r8[py * 2 + px];
    __syncthreads();

    // qr[pixel][action] = conv(r, Wi) at pixel; v0 = max_a qr
    // Wi reads are wave-uniform constant-indexed -> s_load (scalar cache)
    float qr[8][NA];
    #pragma unroll
    for (int py = 0; py < 4; ++py) {
        #pragma unroll
        for (int px = 0; px < 2; ++px) {
            int y = y0 + py, x = x0 + px;
            float rn[9];
            #pragma unroll
            for (int t = 0; t < 9; ++t)
                rn[t] = rlds[(y + t / 3) * VS + (x + t % 3)];
            float vmax = -1e30f;
            #pragma unroll
            for (int a = 0; a < NA; ++a) {
                float acc = 0.f;
                #pragma unroll
                for (int t = 0; t < 9; ++t) acc += Wi[a * 9 + t] * rn[t];
                qr[py * 2 + px][a] = acc;
                vmax = fmaxf(vmax, acc);
            }
            vlds[(y + 1) * VS + (x + 1)] = vmax;
        }
    }
    __syncthreads();

    // ---------------- phase 5: async value iteration ----------------
    // Weights from Wvq arg: uniform + constant-indexed -> SGPRs, hoisted.
    // Inner FMA = v_fmac_f32 v,s,v; LDS pipe only carries vn (12x b64) + 8 writes.
    int checks = 0;
    for (int it = 0; it < K; ++it) {
        float vn[6][4];
        #pragma unroll
        for (int r = 0; r < 6; ++r) {
            const float2* vp = reinterpret_cast<const float2*>(&vlds[(y0 + r) * VS + x0]);
            float2 a0 = vp[0], a1 = vp[1];
            vn[r][0] = a0.x; vn[r][1] = a0.y; vn[r][2] = a1.x; vn[r][3] = a1.y;
        }
        float nv[8];
        #pragma unroll
        for (int p = 0; p < 8; ++p) nv[p] = -1e30f;
        #pragma unroll
        for (int a = 0; a < NA; ++a) {
            #pragma unroll
            for (int py = 0; py < 4; ++py)
                #pragma unroll
                for (int px = 0; px < 2; ++px) {
                    float acc = qr[py * 2 + px][a];
                    #pragma unroll
                    for (int ky = 0; ky < 3; ++ky)
                        #pragma unroll
                        for (int kx = 0; kx < 3; ++kx)
                            acc += Wvq[a * 9 + ky * 3 + kx] * vn[py + ky][px + kx];
                    nv[py * 2 + px] = fmaxf(nv[py * 2 + px], acc);
                }
        }
        bool check = ((it & 3) == 3) || (it == K - 1);
        if (check) {
            bool changed = false;
            #pragma unroll
            for (int py = 0; py < 4; ++py)
                #pragma unroll
                for (int px = 0; px < 2; ++px)
                    changed |= (fabsf(nv[py * 2 + px] - vn[py + 1][px + 1]) > 4e-4f);
            __syncthreads();   // B1: all reads of this sweep done
            #pragma unroll
            for (int py = 0; py < 4; ++py)
                #pragma unroll
                for (int px = 0; px < 2; ++px)
                    vlds[(y0 + py + 1) * VS + (x0 + px + 1)] = nv[py * 2 + px];
            chg[(checks + 1) & 1] = 0;          // prep next slot
            if (changed) chg[checks & 1] = 1;   // benign same-value race
            __syncthreads();   // B2: v + flags visible
            if (chg[checks & 1] == 0) break;    // full sweep with max|dv|<=tol
            ++checks;
        } else {
            // async in-place sweep: no barrier; races benign (contraction)
            #pragma unroll
            for (int py = 0; py < 4; ++py)
                #pragma unroll
                for (int px = 0; px < 2; ++px)
                    vlds[(y0 + py + 1) * VS + (x0 + px + 1)] = nv[py * 2 + px];
            __threadfence_block();   // visibility + defeat LDS caching
        }
    }

    // ---------------- phase 6: attended q + FC (uniform weights direct) -----
    if (tid == 0) {
        int yy = att_y, xx = att_x;
        float q[NA];
        #pragma unroll
        for (int a = 0; a < NA; ++a) {
            float acc = 0.f;
            #pragma unroll
            for (int t = 0; t < 9; ++t) {
                int ly = yy + t / 3, lx = xx + t % 3;
                acc += Wi[a * 9 + t]  * rlds[ly * VS + lx]
                     + Wvq[a * 9 + t] * vlds[ly * VS + lx];
            }
            q[a] = acc;
        }
        #pragma unroll
        for (int n = 0; n < 8; ++n) {
            float o = 0.f;
            #pragma unroll
            for (int a = 0; a < NA; ++a) o += q[a] * Wfc[n * NA + a];
            out[b * 8 + n] = o;
        }
    }

    // keep-alive for ldspad: K = kptr[0] >= 0 always, but the compiler cannot
    // prove it, so the pad (and its occupancy effect) survives DCE. Never runs.
    if (K < 0) {
        ldspad[tid] = (float)tid;
        out[b * 8 + (tid & 7)] = ldspad[(PADF - 1) - tid];
    }
}

// ---------------------------------------------------------------------------
extern "C" void kernel_launch(void* const* d_in, const int* in_sizes, int n_in,
                              void* d_out, int out_size, void* d_ws, size_t ws_size,
                              hipStream_t stream) {
    const int*   s1   = (const int*)d_in[0];
    const int*   s2   = (const int*)d_in[1];
    const float* obs  = (const float*)d_in[2];
    const int*   kptr = (const int*)d_in[3];
    const float* Wh   = (const float*)d_in[4];
    const float* bh   = (const float*)d_in[5];
    const float* Wr   = (const float*)d_in[6];
    const float* Wi   = (const float*)d_in[7];
    const float* Wvq  = (const float*)d_in[8];
    const float* Wfc  = (const float*)d_in[9];
    float* out = (float*)d_out;
    (void)ws_size; (void)d_ws; (void)in_sizes; (void)n_in; (void)out_size;

    vin_fused<<<NB, NT, 0, stream>>>(obs, Wh, bh, Wr, Wi, Wvq, Wfc,
                                     s1, s2, kptr, out);
}